// Round 8
// baseline (750.385 us; speedup 1.0000x reference)
//
#include <hip/hip_runtime.h>
#include <hip/hip_bf16.h>
#include <math.h>

#define NPTS 4096
#define KD   64
#define BR   128                      // rows per block (4 waves x 32 rows)
#define BC   128                      // cols per tile
#define NSPLIT 4                      // column splits (partial LSE per split)
#define CT   (NPTS / (BC * NSPLIT))   // 8 col tiles per block
#define NTHREADS 256
#define BLOG2 (-12.0f)                // -log2(4096)
#define LOG2E 1.4426950408889634f
#define LN2   0.6931471805599453f

typedef __bf16 bf16x8 __attribute__((ext_vector_type(8)));
typedef float  f32x16 __attribute__((ext_vector_type(16)));

// fast transcendentals: raw v_exp_f32 / v_log_f32 (base-2, <=1 ulp)
__device__ __forceinline__ float ex2(float x) {
#if __has_builtin(__builtin_amdgcn_exp2f)
  return __builtin_amdgcn_exp2f(x);
#else
  return exp2f(x);
#endif
}
__device__ __forceinline__ float lg2(float x) {
#if __has_builtin(__builtin_amdgcn_logf)
  return __builtin_amdgcn_logf(x);   // v_log_f32 = log2
#else
  return log2f(x);
#endif
}

struct FusedArgs {
  const unsigned short* X[4];   // bf16 row-major [NPTS][KD]
  const unsigned short* Y[4];
  const float* csq[4];    // 0.5*|y_j|^2 of col-side points of dir d
  const float* pmr[4];    // prev-pass partial max, paired dir
  const float* psr[4];    // prev-pass partial sum, paired dir
  const float* potr[4];   // prev potential of col-side points (paired dir)
  float* potw[4];         // blended potential out (paired dir slot)
  float* pm;              // this pass: [4][NSPLIT][NPTS] partial max (base-2)
  float* ps;              // this pass: [4][NSPLIT][NPTS] partial sum
  float ie2;              // log2(e) / eps_cur
  float elp;              // eps_prev * ln(2)
  float alpha, beta;      // potential blend g = alpha*prev + beta*v
  int mode;               // 0 = init (g = 0, no partials), 1 = merge prev pass
};

// async 16B/lane global->LDS; lds dest = wave-uniform base + lane*16
__device__ __forceinline__ void gll16(const void* g, void* l) {
  __builtin_amdgcn_global_load_lds(
      (const __attribute__((address_space(1))) void*)g,
      (__attribute__((address_space(3))) void*)l, 16, 0, 0);
}

// One softmin pass, all 4 directions via blockIdx.z.
// ROUND-8 delta (sole structural change vs round 7): MFMA shape 16x16x32 ->
// 32x32x16 (fragment mapping verified end-to-end in round 2). Each wave owns
// 32 rows x 128 cols; one B-fragment ds_read_b128 feeds a 16384-MAC MFMA, so
// LDS-read traffic AND MFMA count halve per element. BR 64 -> 128, grid 512
// = 2 blocks/CU, launch_bounds(256,2) -> 256-VGPR cap (acc64+af16+ms32~145,
// no spill; round-6 lesson).
// Y tile staged via global_load_lds, XOR seg swizzle: LDS 16B-seg p of col r
// holds global seg p^(r&7); B read seg (2ks+hh)^(col&7) spreads 64 lanes
// evenly over all 32 banks (8 lanes per 4-bank group = b128 floor).
__global__ __launch_bounds__(NTHREADS, 2)
void fused_softmin(FusedArgs A) {
  __shared__ __align__(16) __bf16 YT[2][BC * KD];   // 2 x 16 KB
  __shared__ __align__(16) float QL[BC * CT];       // 4 KB: this split's q

  const int tid  = threadIdx.x;
  const int lane = tid & 63;
  const int wave = tid >> 6;    // 0..3 : 32-row group
  const int ln   = lane & 31;   // A row / B,C col within 32
  const int hh   = lane >> 5;   // k-half within 16-k step; C row-offset bit
  const int ln7  = ln & 7;
  const int rowblk = blockIdx.x;
  const int split  = blockIdx.y;
  const int dir    = blockIdx.z;

  const __bf16* __restrict__ Xb = (const __bf16*)A.X[dir];
  const __bf16* __restrict__ Yb = (const __bf16*)A.Y[dir];
  const float ie2 = A.ie2;
  const int row0 = rowblk * BR;
  const int col0 = split * (CT * BC);

  // staging geometry: linear idx = it*256 + tid; col = idx>>3, seg = idx&7
  const int srow = tid >> 3;
  const int sseg = tid & 7;

  // issue tile-0 Y staging (async)
#pragma unroll
  for (int it = 0; it < 4; ++it) {
    int r = it * 32 + srow;
    gll16(Yb + (size_t)(col0 + r) * KD + ((sseg ^ (r & 7)) << 3),
          (__bf16*)YT[0] + it * 2048 + wave * 512);
  }

  // A fragments: global -> VGPR, once (round-2 verified layout:
  // row = ln, k-offset = ks*16 + hh*8)
  bf16x8 af[4];
  {
    const __bf16* ap = Xb + (size_t)(row0 + wave * 32 + ln) * KD + hh * 8;
#pragma unroll
    for (int ks = 0; ks < 4; ++ks) {
      union { uint4 u; bf16x8 v; } t;
      t.u = *(const uint4*)(ap + ks * 16);
      af[ks] = t.v;
    }
  }

  // ---- fused merge prologue: build q for this split's 1024 cols ----
  {
    const float* __restrict__ csq = A.csq[dir];
    if (A.mode == 0) {
#pragma unroll
      for (int i = 0; i < 4; ++i) {
        int c = col0 + tid + i * 256;
        QL[tid + i * 256] = BLOG2 - csq[c] * ie2;     // g = 0
      }
    } else {
      const float* __restrict__ pmr = A.pmr[dir];
      const float* __restrict__ psr = A.psr[dir];
      const float* __restrict__ potr = A.potr[dir];
      float* __restrict__ potw = A.potw[dir];
#pragma unroll
      for (int i = 0; i < 4; ++i) {
        int c = col0 + tid + i * 256;
        float m0 = pmr[0 * NPTS + c], m1 = pmr[1 * NPTS + c];
        float m2 = pmr[2 * NPTS + c], m3 = pmr[3 * NPTS + c];
        float s0 = psr[0 * NPTS + c], s1 = psr[1 * NPTS + c];
        float s2 = psr[2 * NPTS + c], s3 = psr[3 * NPTS + c];
        float m4 = fmaxf(fmaxf(m0, m1), fmaxf(m2, m3));
        float s4 = s0 * ex2(m0 - m4) + s1 * ex2(m1 - m4) +
                   s2 * ex2(m2 - m4) + s3 * ex2(m3 - m4);
        float lse2 = m4 + lg2(s4);
        float xsq = csq[c];
        float v = xsq - A.elp * lse2;                 // elp = eps_prev*ln2
        float g = A.alpha * potr[c] + A.beta * v;
        if (rowblk == 0) potw[c] = g;
        QL[tid + i * 256] = BLOG2 + (g - xsq) * ie2;
      }
    }
  }

  float m[16], s[16];
#pragma unroll
  for (int r = 0; r < 16; ++r) { m[r] = -__builtin_inff(); s[r] = 0.f; }

  __syncthreads();   // drains tile-0 staging; QL visible to all waves

  for (int tile = 0; tile < CT; ++tile) {
    const int cb = tile & 1;

    // async prefetch next tile (drained by end-of-tile barrier)
    if (tile < CT - 1) {
      const int nc0 = col0 + (tile + 1) * BC;
#pragma unroll
      for (int it = 0; it < 4; ++it) {
        int r = it * 32 + srow;
        gll16(Yb + (size_t)(nc0 + r) * KD + ((sseg ^ (r & 7)) << 3),
              (__bf16*)YT[cb ^ 1] + it * 2048 + wave * 512);
      }
    }

    float qv[4];
#pragma unroll
    for (int ct = 0; ct < 4; ++ct)
      qv[ct] = QL[tile * BC + ct * 32 + ln];

    f32x16 acc[4];
#pragma unroll
    for (int ct = 0; ct < 4; ++ct)
#pragma unroll
      for (int i = 0; i < 16; ++i) acc[ct][i] = 0.f;

    const __bf16* ybase = YT[cb] + ln * KD;
#pragma unroll
    for (int ks = 0; ks < 4; ++ks) {
      const int sg = ((ks << 1) | hh) ^ ln7;
#pragma unroll
      for (int ct = 0; ct < 4; ++ct) {
        union { uint4 u; bf16x8 v; } bb;
        bb.u = *(const uint4*)(ybase + ct * 32 * KD + sg * 8);
        acc[ct] = __builtin_amdgcn_mfma_f32_32x32x16_bf16(af[ks], bb.v, acc[ct], 0, 0, 0);
      }
    }

    // online-softmax epilogue over the 32x32 C layout (16 regs/lane)
#pragma unroll
    for (int r = 0; r < 16; ++r) {
      float l0 = fmaf(acc[0][r], ie2, qv[0]);
      float l1 = fmaf(acc[1][r], ie2, qv[1]);
      float l2 = fmaf(acc[2][r], ie2, qv[2]);
      float l3 = fmaf(acc[3][r], ie2, qv[3]);
      float mn = fmaxf(m[r], fmaxf(fmaxf(l0, l1), fmaxf(l2, l3)));
      float sadd = ex2(l0 - mn) + ex2(l1 - mn) + ex2(l2 - mn) + ex2(l3 - mn);
      s[r] = fmaf(s[r], ex2(m[r] - mn), sadd);
      m[r] = mn;
    }
    __syncthreads();
  }

  // cross-lane merge over the 32 col-owner lanes (masks 1..16 keep hh)
#pragma unroll
  for (int r = 0; r < 16; ++r) {
#pragma unroll
    for (int d = 1; d < 32; d <<= 1) {
      float mo = __shfl_xor(m[r], d, 64);
      float so = __shfl_xor(s[r], d, 64);
      float mn = fmaxf(m[r], mo);
      s[r] = ex2(m[r] - mn) * s[r] + ex2(mo - mn) * so;
      m[r] = mn;
    }
  }
  if (ln == 0) {
#pragma unroll
    for (int r = 0; r < 16; ++r) {
      int row = row0 + wave * 32 + (r & 3) + ((r >> 2) << 3) + (hh << 2);
      size_t gi = (size_t)(dir * NSPLIT + split) * NPTS + row;
      A.pm[gi] = m[r];
      A.ps[gi] = s[r];
    }
  }
}

// sqnorms + bf16 conversion
__global__ void prep(const float* __restrict__ x, const float* __restrict__ y,
                     float* xs, float* ys,
                     unsigned short* xb, unsigned short* yb) {
  int gid = blockIdx.x * blockDim.x + threadIdx.x;  // 0..8191
  int isx = (gid < NPTS) ? 1 : 0;
  const float* p = isx ? x : y;
  int row = gid & (NPTS - 1);
  const float4* r4 = (const float4*)(p + (size_t)row * KD);
  unsigned short* ob = (isx ? xb : yb) + (size_t)row * KD;
  float s = 0.f;
#pragma unroll
  for (int i = 0; i < 16; ++i) {
    float4 v = r4[i];
    s += v.x * v.x + v.y * v.y + v.z * v.z + v.w * v.w;
    union { __bf16 h[4]; uint2 u; } t;
    t.h[0] = (__bf16)v.x; t.h[1] = (__bf16)v.y;
    t.h[2] = (__bf16)v.z; t.h[3] = (__bf16)v.w;
    *(uint2*)(ob + i * 4) = t.u;
  }
  (isx ? xs : ys)[row] = 0.5f * s;
}

// Merge the FINAL extrapolation pass's partials for all 4 dirs and reduce:
// out = (1/N) * sum_rows[(f0 - f2) + (f1 - f3)]
__global__ void final_reduce(const float* __restrict__ pm,
                             const float* __restrict__ ps,
                             const float* __restrict__ xsx,
                             const float* __restrict__ xsy,
                             float elpF, float* out) {
  __shared__ float red[256];
  int t = threadIdx.x;
  float acc = 0.f;
  for (int r = t; r < NPTS; r += 256) {
#pragma unroll
    for (int d = 0; d < 4; ++d) {
      float m0 = pm[(size_t)(d * NSPLIT + 0) * NPTS + r];
      float m1 = pm[(size_t)(d * NSPLIT + 1) * NPTS + r];
      float m2 = pm[(size_t)(d * NSPLIT + 2) * NPTS + r];
      float m3 = pm[(size_t)(d * NSPLIT + 3) * NPTS + r];
      float s0 = ps[(size_t)(d * NSPLIT + 0) * NPTS + r];
      float s1 = ps[(size_t)(d * NSPLIT + 1) * NPTS + r];
      float s2 = ps[(size_t)(d * NSPLIT + 2) * NPTS + r];
      float s3 = ps[(size_t)(d * NSPLIT + 3) * NPTS + r];
      float m4 = fmaxf(fmaxf(m0, m1), fmaxf(m2, m3));
      float s4 = s0 * ex2(m0 - m4) + s1 * ex2(m1 - m4) +
                 s2 * ex2(m2 - m4) + s3 * ex2(m3 - m4);
      float lse2 = m4 + lg2(s4);
      float xsq = (d == 0 || d == 2) ? xsx[r] : xsy[r];
      float f = xsq - elpF * lse2;
      acc += (d < 2) ? f : -f;
    }
  }
  red[t] = acc;
  __syncthreads();
  for (int off = 128; off > 0; off >>= 1) {
    if (t < off) red[t] += red[t + off];
    __syncthreads();
  }
  if (t == 0) out[0] = red[0] * (1.0f / NPTS);
}

extern "C" void kernel_launch(void* const* d_in, const int* in_sizes, int n_in,
                              void* d_out, int out_size, void* d_ws, size_t ws_size,
                              hipStream_t stream) {
  const float* x = (const float*)d_in[0];
  const float* y = (const float*)d_in[1];
  float* out = (float*)d_out;
  float* w = (float*)d_ws;

  // ws layout (float slots); total 138*NPTS ~ 2.2 MB
  float* xs_x = w;                         // [NPTS]
  float* xs_y = w + NPTS;                  // [NPTS]
  float* pot0 = w + 2 * NPTS;              // [4][NPTS] potential ping
  float* pot1 = w + 6 * NPTS;              // [4][NPTS] potential pong
  float* pm0  = w + 10 * NPTS;             // [4][NSPLIT][NPTS]
  float* ps0  = w + 26 * NPTS;
  float* pm1  = w + 42 * NPTS;
  float* ps1  = w + 58 * NPTS;
  unsigned short* xb = (unsigned short*)(w + 74 * NPTS);   // [NPTS][KD] bf16
  unsigned short* yb = (unsigned short*)(w + 106 * NPTS);  // [NPTS][KD] bf16
  float* pmb[2] = {pm0, pm1};
  float* psb[2] = {ps0, ps1};
  float* potb[2] = {pot0, pot1};

  // geomloss epsilon_schedule(p=2, diameter=20, blur=0.01, scaling=0.7)
  double eps_list[32];
  int neps = 0;
  {
    double start = 2.0 * log(20.0);
    double stop  = 2.0 * log(0.01);
    double step  = 2.0 * log(0.7);
    eps_list[neps++] = 400.0;
    int cnt = (int)ceil((stop - start) / step);  // 22
    for (int i = 0; i < cnt && neps < 30; ++i) eps_list[neps++] = exp(start + (double)i * step);
    eps_list[neps++] = 1e-4;                     // neps == 24
  }

  // dir 0: ft (rows x, cols y); dir 1: gt (rows y, cols x)
  // dir 2: f_aa (x,x); dir 3: g_bb (y,y).  qpair = paired dir whose ROWS are
  // this dir's COLS: {1,0,2,3}.
  const unsigned short* Xd[4] = {xb, yb, xb, yb};
  const unsigned short* Yd[4] = {yb, xb, xb, yb};
  const float* YSQd[4] = {xs_y, xs_x, xs_x, xs_y};   // col-side sqnorms
  const int qpair[4] = {1, 0, 2, 3};

  prep<<<dim3(32), dim3(256), 0, stream>>>(x, y, xs_x, xs_y, xb, yb);

  dim3 fgrid(NPTS / BR, NSPLIT, 4);   // 32 x 4 x 4 = 512 blocks = 2/CU

  // eps used by launch k (k = 0 init, 1..24 loop, 25 final extrapolation)
  double ecur[26];
  ecur[0] = eps_list[0];
  for (int k = 1; k <= 24; ++k) ecur[k] = eps_list[k - 1];
  ecur[25] = eps_list[neps - 1];

  for (int k = 0; k <= 25; ++k) {
    FusedArgs fa;
    for (int d = 0; d < 4; ++d) {
      fa.X[d] = Xd[d]; fa.Y[d] = Yd[d]; fa.csq[d] = YSQd[d];
      int p = qpair[d];
      fa.pmr[d]  = pmb[(k + 1) & 1] + (size_t)p * NSPLIT * NPTS;
      fa.psr[d]  = psb[(k + 1) & 1] + (size_t)p * NSPLIT * NPTS;
      fa.potr[d] = potb[(k + 1) & 1] + (size_t)p * NPTS;
      fa.potw[d] = potb[k & 1] + (size_t)p * NPTS;
    }
    fa.pm = pmb[k & 1];
    fa.ps = psb[k & 1];
    fa.ie2 = (float)(LOG2E / ecur[k]);
    fa.elp = (k == 0) ? 0.f : (float)(ecur[k - 1] * LN2);
    fa.alpha = (k <= 1) ? 0.f : 0.5f;
    fa.beta  = (k <= 1) ? 1.f : 0.5f;
    fa.mode  = (k == 0) ? 0 : 1;
    fused_softmin<<<fgrid, dim3(NTHREADS), 0, stream>>>(fa);
  }

  final_reduce<<<dim3(1), dim3(256), 0, stream>>>(
      pmb[25 & 1], psb[25 & 1], xs_x, xs_y,
      (float)(eps_list[neps - 1] * LN2), out);
}